// Round 7
// baseline (465.909 us; speedup 1.0000x reference)
//
#include <hip/hip_runtime.h>
#include <hip/hip_fp16.h>

// GCN 3->32->32->1, N=100K, E=6.4M (+self loops).
// R6 lesson: k_scat's temporally-scattered 4B writes cost 170MB of 32B
// sectors (137us). R7: k_bsort sorts each 5000-edge chunk fully in LDS
// (count/scan/permute), then streams per-bucket RUNS out coalesced -> L2
// write-back can merge runs across chunks (packed fits 32MB agg L2).
// Everything else carried: fp16 g, 8-wide unrolled k_l2, fused k_sort,
// node-parallel layers, zero global atomics anywhere.

#define BLK 256
#define SB 1280          // chunks; SB*CHUNK == E exactly
#define CHUNK 5000
#define BKT 128          // nodes per bucket
#define NBKT 782         // ceil(100000/128)
#define MAXNB 1024       // scanB width >= NBKT
#define BUFSZ 15360      // k_sort bucket buffer (mean 8192, ~79 sigma)

// ---- pass 1: per-chunk histogram over dst buckets (LDS, no global atomics)
__global__ void k_hist(const int* __restrict__ dst, int* __restrict__ hist, int E) {
    __shared__ int lh[NBKT];
    for (int b = threadIdx.x; b < NBKT; b += blockDim.x) lh[b] = 0;
    __syncthreads();
    int beg = blockIdx.x * CHUNK, end = min(E, beg + CHUNK);
    for (int e = beg + threadIdx.x; e < end; e += blockDim.x)
        atomicAdd(&lh[dst[e] >> 7], 1);
    __syncthreads();
    for (int b = threadIdx.x; b < NBKT; b += blockDim.x)
        hist[(size_t)blockIdx.x * NBKT + b] = lh[b];
}

// ---- scan A: per bucket, exclusive-scan its SB chunk-counts (shfl, 5 items/thr)
__global__ void k_scanA(int* __restrict__ hist, int* __restrict__ btot, int NB) {
    int b = blockIdx.x, t = threadIdx.x;          // 256 threads * 5 items = 1280
    int base = t * 5;
    int v0 = hist[(size_t)(base + 0) * NB + b];
    int v1 = hist[(size_t)(base + 1) * NB + b];
    int v2 = hist[(size_t)(base + 2) * NB + b];
    int v3 = hist[(size_t)(base + 3) * NB + b];
    int v4 = hist[(size_t)(base + 4) * NB + b];
    int s = v0 + v1 + v2 + v3 + v4;
    int lane = t & 63, w = t >> 6;
    int x = s;
#pragma unroll
    for (int off = 1; off < 64; off <<= 1) {
        int u = __shfl_up(x, off, 64);
        if (lane >= off) x += u;
    }
    __shared__ int wsum[4];
    if (lane == 63) wsum[w] = x;
    __syncthreads();
    int woff = 0;
    for (int k = 0; k < 4; k++) woff += (k < w) ? wsum[k] : 0;
    int run = woff + x - s;                       // exclusive prefix for item 0
    hist[(size_t)(base + 0) * NB + b] = run;  run += v0;
    hist[(size_t)(base + 1) * NB + b] = run;  run += v1;
    hist[(size_t)(base + 2) * NB + b] = run;  run += v2;
    hist[(size_t)(base + 3) * NB + b] = run;  run += v3;
    hist[(size_t)(base + 4) * NB + b] = run;  run += v4;
    if (t == 255) btot[b] = run;
}

// ---- scan B: exclusive-scan bucket totals -> bucket base offsets
__global__ void k_scanB(const int* __restrict__ btot, int* __restrict__ bbase,
                        int NB, int E) {
    __shared__ int sh[MAXNB];
    int t = threadIdx.x;
    int v = (t < NB) ? btot[t] : 0;
    sh[t] = v;
    __syncthreads();
    for (int off = 1; off < MAXNB; off <<= 1) {
        int u = (t >= off) ? sh[t - off] : 0;
        __syncthreads();
        sh[t] += u;
        __syncthreads();
    }
    if (t < NB) bbase[t] = sh[t] - v;
    if (t == 0) bbase[NB] = E;
}

// ---- pass 2: LDS chunk-sort by bucket, stream runs out (coalesced writes)
__global__ void k_bsort(const int* __restrict__ src, const int* __restrict__ dst,
                        const int* __restrict__ hist, const int* __restrict__ bbase,
                        unsigned int* __restrict__ packed, int E) {
    __shared__ unsigned int bufA[CHUNK];
    __shared__ unsigned int bufB[CHUNK];
    __shared__ unsigned short binarr[CHUNK];
    __shared__ int cnt[NBKT];
    __shared__ int off[NBKT];
    __shared__ int cur[NBKT];
    __shared__ int gbase[NBKT];
    __shared__ int wsum[4];
    int t = threadIdx.x;
    int beg = blockIdx.x * CHUNK;                 // every chunk exactly CHUNK edges
    for (int b = t; b < NBKT; b += blockDim.x) {
        cnt[b] = 0;
        gbase[b] = bbase[b] + hist[(size_t)blockIdx.x * NBKT + b];
    }
    __syncthreads();
    // phase a: coalesced read, pack, bin, count
    for (int i = t; i < CHUNK; i += blockDim.x) {
        int d = dst[beg + i];
        int s = src[beg + i];
        int b = d >> 7;
        bufA[i] = (unsigned)s | ((unsigned)(d & 127) << 17);
        binarr[i] = (unsigned short)b;
        atomicAdd(&cnt[b], 1);
    }
    __syncthreads();
    // phase b: exclusive scan of 782 counts (4 items/thread, shfl)
    {
        int base = t * 4;
        int v0 = (base + 0 < NBKT) ? cnt[base + 0] : 0;
        int v1 = (base + 1 < NBKT) ? cnt[base + 1] : 0;
        int v2 = (base + 2 < NBKT) ? cnt[base + 2] : 0;
        int v3 = (base + 3 < NBKT) ? cnt[base + 3] : 0;
        int s = v0 + v1 + v2 + v3;
        int lane = t & 63, w = t >> 6;
        int x = s;
#pragma unroll
        for (int o = 1; o < 64; o <<= 1) {
            int u = __shfl_up(x, o, 64);
            if (lane >= o) x += u;
        }
        if (lane == 63) wsum[w] = x;
        __syncthreads();
        int woff = 0;
        for (int k = 0; k < 4; k++) woff += (k < w) ? wsum[k] : 0;
        int run = woff + x - s;
        if (base + 0 < NBKT) { off[base + 0] = run; cur[base + 0] = run; } run += v0;
        if (base + 1 < NBKT) { off[base + 1] = run; cur[base + 1] = run; } run += v1;
        if (base + 2 < NBKT) { off[base + 2] = run; cur[base + 2] = run; } run += v2;
        if (base + 3 < NBKT) { off[base + 3] = run; cur[base + 3] = run; } run += v3;
    }
    __syncthreads();
    // phase c: permute into bucket-grouped order
    for (int i = t; i < CHUNK; i += blockDim.x) {
        int b = binarr[i];
        int pos = atomicAdd(&cur[b], 1);
        bufB[pos] = bufA[i];
    }
    __syncthreads();
    // phase d: stream each bucket's run to global (coalesced within run)
    int wv = t >> 6, lane = t & 63;
    for (int b = wv; b < NBKT; b += 4) {
        int c = cnt[b], o = off[b], gb = gbase[b];
        for (int k = lane; k < c; k += 64)
            packed[gb + k] = bufB[o + k];
    }
}

// ---- fused: per-bucket count + scan + dis/y4/rowptr + in-place node sort
__global__ void k_sort(unsigned int* __restrict__ packed, const int* __restrict__ bbase,
                       const float* __restrict__ x, float* __restrict__ dis,
                       float4* __restrict__ y4, int* __restrict__ rowptr, int N, int E) {
    __shared__ unsigned int buf[BUFSZ];
    __shared__ int cnt[BKT];
    __shared__ int sc[BKT];
    __shared__ int cur[BKT];
    int b = blockIdx.x, t = threadIdx.x;
    int beg = bbase[b], end = bbase[b + 1];
    int len = end - beg;
    for (int i = t; i < len; i += blockDim.x) buf[i] = packed[beg + i];
    if (t < BKT) cnt[t] = 0;
    __syncthreads();
    for (int i = t; i < len; i += blockDim.x)
        atomicAdd(&cnt[buf[i] >> 17], 1);
    __syncthreads();
    int v = 0;
    if (t < BKT) { v = cnt[t]; sc[t] = v; }
    __syncthreads();
    for (int off = 1; off < BKT; off <<= 1) {
        int u = 0;
        if (t < BKT && t >= off) u = sc[t - off];
        __syncthreads();
        if (t < BKT) sc[t] += u;
        __syncthreads();
    }
    if (t < BKT) {
        int excl = sc[t] - v;
        cur[t] = excl;
        int gi = b * BKT + t;
        if (gi < N) {
            rowptr[gi] = beg + excl;
            float di = rsqrtf((float)v + 1.0f);      // + self loop
            dis[gi] = di;
            float4 y;
            y.x = di * x[3 * gi + 0];
            y.y = di * x[3 * gi + 1];
            y.z = di * x[3 * gi + 2];
            y.w = 0.0f;
            y4[gi] = y;
        }
    }
    __syncthreads();
    for (int i = t; i < len; i += blockDim.x) {
        unsigned vv = buf[i];
        int pos = atomicAdd(&cur[vv >> 17], 1);      // LDS atomic
        packed[beg + pos] = vv & 0x1FFFF;            // plain src id, node-sorted
    }
    if (b == 0 && t == 0) rowptr[N] = E;
}

// ---- layer 1: node-parallel, 32 lanes/node gather y4 (1.6MB, L2-resident)
__global__ void k_l1(const unsigned int* __restrict__ csr, const int* __restrict__ rowptr,
                     const float4* __restrict__ y4, const float* __restrict__ dis,
                     const float* __restrict__ W1, const float* __restrict__ b1,
                     __half* __restrict__ g, int N) {
    int t = blockIdx.x * blockDim.x + threadIdx.x;
    int i = t >> 5, j = t & 31;
    if (i >= N) return;
    int beg = rowptr[i], end = rowptr[i + 1];
    float ax = 0.f, ay = 0.f, az = 0.f;
    for (int e = beg + j; e < end; e += 32) {
        float4 yv = y4[csr[e]];
        ax += yv.x; ay += yv.y; az += yv.z;
    }
#pragma unroll
    for (int m = 16; m >= 1; m >>= 1) {
        ax += __shfl_xor(ax, m, 32);
        ay += __shfl_xor(ay, m, 32);
        az += __shfl_xor(az, m, 32);
    }
    float di = dis[i];
    float4 ys = y4[i];                               // self loop (pre-scaled)
    float a0 = di * (ax + ys.x);
    float a1 = di * (ay + ys.y);
    float a2 = di * (az + ys.z);
    float h = b1[j] + a0 * W1[j] + a1 * W1[32 + j] + a2 * W1[64 + j];
    g[(size_t)i * 32 + j] = __float2half(di * fmaxf(h, 0.f));
}

// ---- layer 2 (+L3 projection): 8-wide unrolled fp16 row gathers
__global__ void k_l2(const unsigned int* __restrict__ csr, const int* __restrict__ rowptr,
                     const __half* __restrict__ g, const float* __restrict__ dis,
                     const float* __restrict__ W2, const float* __restrict__ b2,
                     const float* __restrict__ W3, float* __restrict__ q, int N) {
    int t = blockIdx.x * blockDim.x + threadIdx.x;
    int i = t >> 5, j = t & 31;
    if (i >= N) return;
    int beg = rowptr[i], end = rowptr[i + 1];
    float a0 = 0.f, a1 = 0.f, a2 = 0.f, a3 = 0.f;
    float a4 = 0.f, a5 = 0.f, a6 = 0.f, a7 = 0.f;
    for (int k0 = beg; k0 < end; k0 += 32) {
        int e = k0 + j;
        int myedge = (e < end) ? (int)csr[e] : 0;    // coalesced chunk load
        int cnt = min(32, end - k0);
        int t2 = 0;
        for (; t2 + 8 <= cnt; t2 += 8) {             // 8 independent gathers in flight
            int s0 = __shfl(myedge, t2 + 0, 32);
            int s1 = __shfl(myedge, t2 + 1, 32);
            int s2 = __shfl(myedge, t2 + 2, 32);
            int s3 = __shfl(myedge, t2 + 3, 32);
            int s4 = __shfl(myedge, t2 + 4, 32);
            int s5 = __shfl(myedge, t2 + 5, 32);
            int s6 = __shfl(myedge, t2 + 6, 32);
            int s7 = __shfl(myedge, t2 + 7, 32);
            a0 += __half2float(g[(size_t)s0 * 32 + j]);
            a1 += __half2float(g[(size_t)s1 * 32 + j]);
            a2 += __half2float(g[(size_t)s2 * 32 + j]);
            a3 += __half2float(g[(size_t)s3 * 32 + j]);
            a4 += __half2float(g[(size_t)s4 * 32 + j]);
            a5 += __half2float(g[(size_t)s5 * 32 + j]);
            a6 += __half2float(g[(size_t)s6 * 32 + j]);
            a7 += __half2float(g[(size_t)s7 * 32 + j]);
        }
        for (; t2 < cnt; t2++) {
            int s = __shfl(myedge, t2, 32);
            a0 += __half2float(g[(size_t)s * 32 + j]);
        }
    }
    float acc = ((a0 + a1) + (a2 + a3)) + ((a4 + a5) + (a6 + a7));
    float di = dis[i];
    float a = di * (acc + __half2float(g[(size_t)i * 32 + j]));   // + self loop
    float o = b2[j];
#pragma unroll
    for (int k = 0; k < 32; k++)
        o += __shfl(a, k, 32) * W2[k * 32 + j];
    float h2 = fmaxf(o, 0.f);
    float c = h2 * W3[j];
#pragma unroll
    for (int m = 16; m >= 1; m >>= 1)
        c += __shfl_xor(c, m, 32);
    if (j == 0) q[i] = di * c;                       // q = dis * p
}

// ---- layer 3: node-parallel scalar q gathers (q 400KB, L2-resident)
__global__ void k_l3(const unsigned int* __restrict__ csr, const int* __restrict__ rowptr,
                     const float* __restrict__ q, const float* __restrict__ dis,
                     const float* __restrict__ b3, float* __restrict__ out, int N) {
    int t = blockIdx.x * blockDim.x + threadIdx.x;
    int i = t >> 5, j = t & 31;
    if (i >= N) return;
    int beg = rowptr[i], end = rowptr[i + 1];
    float acc = 0.f;
    for (int e = beg + j; e < end; e += 32)
        acc += q[csr[e]];
#pragma unroll
    for (int m = 16; m >= 1; m >>= 1)
        acc += __shfl_xor(acc, m, 32);
    if (j == 0) out[i] = dis[i] * (acc + q[i]) + b3[0];
}

extern "C" void kernel_launch(void* const* d_in, const int* in_sizes, int n_in,
                              void* d_out, int out_size, void* d_ws, size_t ws_size,
                              hipStream_t stream) {
    const float* x  = (const float*)d_in[0];
    const int*   ei = (const int*)d_in[1];
    const float* W1 = (const float*)d_in[2];
    const float* b1 = (const float*)d_in[3];
    const float* W2 = (const float*)d_in[4];
    const float* b2 = (const float*)d_in[5];
    const float* W3 = (const float*)d_in[6];
    const float* b3 = (const float*)d_in[7];
    float* out = (float*)d_out;

    int N = in_sizes[0] / 3;
    int E = in_sizes[1] / 2;
    const int* src = ei;
    const int* dst = ei + E;

    // workspace (all init done in-kernel; no memset needed)
    char* w = (char*)d_ws;
    int*   hist   = (int*)w;       w += (size_t)SB * NBKT * 4;      // 4.0 MB
    int*   btot   = (int*)w;       w += (size_t)MAXNB * 4;
    int*   bbase  = (int*)w;       w += (size_t)(MAXNB + 1) * 4;
    int*   rowptr = (int*)w;       w += (size_t)(N + 1) * 4;
    float* dis    = (float*)w;     w += (size_t)N * 4;
    float* y4     = (float*)w;     w += (size_t)N * 16;
    __half* g     = (__half*)w;    w += (size_t)N * 32 * 2;          // 6.4 MB fp16
    float* q      = (float*)w;     w += (size_t)N * 4;
    unsigned int* packed = (unsigned int*)w;  w += (size_t)E * 4;    // 25.6 MB

    k_hist <<<SB, BLK, 0, stream>>>(dst, hist, E);
    k_scanA<<<NBKT, BLK, 0, stream>>>(hist, btot, NBKT);
    k_scanB<<<1, MAXNB, 0, stream>>>(btot, bbase, NBKT, E);
    k_bsort<<<SB, BLK, 0, stream>>>(src, dst, hist, bbase, packed, E);
    k_sort <<<NBKT, BLK, 0, stream>>>(packed, bbase, x, dis, (float4*)y4, rowptr, N, E);

    long long tn = (long long)N * 32;
    unsigned gn = (unsigned)((tn + BLK - 1) / BLK);
    k_l1<<<gn, BLK, 0, stream>>>(packed, rowptr, (const float4*)y4, dis, W1, b1, g, N);
    k_l2<<<gn, BLK, 0, stream>>>(packed, rowptr, g, dis, W2, b2, W3, q, N);
    k_l3<<<gn, BLK, 0, stream>>>(packed, rowptr, q, dis, b3, out, N);
}

// Round 8
// 367.298 us; speedup vs baseline: 1.2685x; 1.2685x over previous
//
#include <hip/hip_runtime.h>
#include <hip/hip_fp16.h>

// GCN 3->32->32->1, N=100K, E=6.4M (+self loops).
// R7 lesson: k_bsort's per-bucket wave streaming had ~6/64 lanes active
// (runs avg 6.4) at 2 blocks/CU -> 153us despite WRITE 170->52MB win.
// R8: (a) full-lane phase d via binarr2 (sorted-position iteration,
// dest = gbase[b]+i-off[b]); (b) LDS 63->42.5KB (drop bufA; phase c
// re-reads src/dst from L2-hot lines) -> 3 blocks/CU; (c) int4 dst loads.
// Carried: fp16 g, 8-wide unrolled k_l2, fused k_sort, node-parallel layers,
// zero global atomics anywhere.

#define BLK 256
#define SB 1280          // chunks; SB*CHUNK == E exactly
#define CHUNK 5000
#define BKT 128          // nodes per bucket
#define NBKT 782         // ceil(100000/128)
#define MAXNB 1024       // scanB width >= NBKT
#define BUFSZ 15360      // k_sort bucket buffer (mean 8192, ~79 sigma)

// ---- pass 1: per-chunk histogram over dst buckets (LDS, int4 loads)
__global__ void k_hist(const int* __restrict__ dst, int* __restrict__ hist, int E) {
    __shared__ int lh[NBKT];
    for (int b = threadIdx.x; b < NBKT; b += blockDim.x) lh[b] = 0;
    __syncthreads();
    int beg = blockIdx.x * CHUNK;
    int end = min(E, beg + CHUNK);
    int nq = (end - beg) >> 2;                    // full int4 quads
    const int4* d4 = (const int4*)(dst + beg);
    for (int i = threadIdx.x; i < nq; i += blockDim.x) {
        int4 d = d4[i];
        atomicAdd(&lh[d.x >> 7], 1);
        atomicAdd(&lh[d.y >> 7], 1);
        atomicAdd(&lh[d.z >> 7], 1);
        atomicAdd(&lh[d.w >> 7], 1);
    }
    for (int e = beg + (nq << 2) + threadIdx.x; e < end; e += blockDim.x)
        atomicAdd(&lh[dst[e] >> 7], 1);
    __syncthreads();
    for (int b = threadIdx.x; b < NBKT; b += blockDim.x)
        hist[(size_t)blockIdx.x * NBKT + b] = lh[b];
}

// ---- scan A: per bucket, exclusive-scan its SB chunk-counts (shfl, 5 items/thr)
__global__ void k_scanA(int* __restrict__ hist, int* __restrict__ btot, int NB) {
    int b = blockIdx.x, t = threadIdx.x;          // 256 threads * 5 items = 1280
    int base = t * 5;
    int v0 = hist[(size_t)(base + 0) * NB + b];
    int v1 = hist[(size_t)(base + 1) * NB + b];
    int v2 = hist[(size_t)(base + 2) * NB + b];
    int v3 = hist[(size_t)(base + 3) * NB + b];
    int v4 = hist[(size_t)(base + 4) * NB + b];
    int s = v0 + v1 + v2 + v3 + v4;
    int lane = t & 63, w = t >> 6;
    int x = s;
#pragma unroll
    for (int off = 1; off < 64; off <<= 1) {
        int u = __shfl_up(x, off, 64);
        if (lane >= off) x += u;
    }
    __shared__ int wsum[4];
    if (lane == 63) wsum[w] = x;
    __syncthreads();
    int woff = 0;
    for (int k = 0; k < 4; k++) woff += (k < w) ? wsum[k] : 0;
    int run = woff + x - s;                       // exclusive prefix for item 0
    hist[(size_t)(base + 0) * NB + b] = run;  run += v0;
    hist[(size_t)(base + 1) * NB + b] = run;  run += v1;
    hist[(size_t)(base + 2) * NB + b] = run;  run += v2;
    hist[(size_t)(base + 3) * NB + b] = run;  run += v3;
    hist[(size_t)(base + 4) * NB + b] = run;  run += v4;
    if (t == 255) btot[b] = run;
}

// ---- scan B: exclusive-scan bucket totals -> bucket base offsets
__global__ void k_scanB(const int* __restrict__ btot, int* __restrict__ bbase,
                        int NB, int E) {
    __shared__ int sh[MAXNB];
    int t = threadIdx.x;
    int v = (t < NB) ? btot[t] : 0;
    sh[t] = v;
    __syncthreads();
    for (int off = 1; off < MAXNB; off <<= 1) {
        int u = (t >= off) ? sh[t - off] : 0;
        __syncthreads();
        sh[t] += u;
        __syncthreads();
    }
    if (t < NB) bbase[t] = sh[t] - v;
    if (t == 0) bbase[NB] = E;
}

// ---- pass 2: LDS chunk-sort by bucket, full-lane sorted-order streaming
__global__ void k_bsort(const int* __restrict__ src, const int* __restrict__ dst,
                        const int* __restrict__ hist, const int* __restrict__ bbase,
                        unsigned int* __restrict__ packed, int E) {
    __shared__ unsigned int bufB[CHUNK];          // 20 KB
    __shared__ unsigned short binarr2[CHUNK];     // 10 KB (bucket of sorted pos)
    __shared__ int cnt[NBKT];
    __shared__ int off[NBKT];
    __shared__ int cur[NBKT];
    __shared__ int gbase[NBKT];
    __shared__ int wsum[4];
    int t = threadIdx.x;
    int beg = blockIdx.x * CHUNK;
    int end = min(E, beg + CHUNK);
    int len = end - beg;
    for (int b = t; b < NBKT; b += blockDim.x) {
        cnt[b] = 0;
        gbase[b] = bbase[b] + hist[(size_t)blockIdx.x * NBKT + b];
    }
    __syncthreads();
    // phase a: count (int4 loads)
    {
        int nq = len >> 2;
        const int4* d4 = (const int4*)(dst + beg);
        for (int i = t; i < nq; i += blockDim.x) {
            int4 d = d4[i];
            atomicAdd(&cnt[d.x >> 7], 1);
            atomicAdd(&cnt[d.y >> 7], 1);
            atomicAdd(&cnt[d.z >> 7], 1);
            atomicAdd(&cnt[d.w >> 7], 1);
        }
        for (int i = (nq << 2) + t; i < len; i += blockDim.x)
            atomicAdd(&cnt[dst[beg + i] >> 7], 1);
    }
    __syncthreads();
    // phase b: exclusive scan of 782 counts (4 items/thread, shfl)
    {
        int base = t * 4;
        int v0 = (base + 0 < NBKT) ? cnt[base + 0] : 0;
        int v1 = (base + 1 < NBKT) ? cnt[base + 1] : 0;
        int v2 = (base + 2 < NBKT) ? cnt[base + 2] : 0;
        int v3 = (base + 3 < NBKT) ? cnt[base + 3] : 0;
        int s = v0 + v1 + v2 + v3;
        int lane = t & 63, w = t >> 6;
        int x = s;
#pragma unroll
        for (int o = 1; o < 64; o <<= 1) {
            int u = __shfl_up(x, o, 64);
            if (lane >= o) x += u;
        }
        if (lane == 63) wsum[w] = x;
        __syncthreads();
        int woff = 0;
        for (int k = 0; k < 4; k++) woff += (k < w) ? wsum[k] : 0;
        int run = woff + x - s;
        if (base + 0 < NBKT) { off[base + 0] = run; cur[base + 0] = run; } run += v0;
        if (base + 1 < NBKT) { off[base + 1] = run; cur[base + 1] = run; } run += v1;
        if (base + 2 < NBKT) { off[base + 2] = run; cur[base + 2] = run; } run += v2;
        if (base + 3 < NBKT) { off[base + 3] = run; cur[base + 3] = run; } run += v3;
    }
    __syncthreads();
    // phase c: permute into bucket-grouped order (src/dst re-read hits L2)
    for (int i = t; i < len; i += blockDim.x) {
        int d = dst[beg + i];
        int s = src[beg + i];
        int b = d >> 7;
        int pos = atomicAdd(&cur[b], 1);
        bufB[pos] = (unsigned)s | ((unsigned)(d & 127) << 17);
        binarr2[pos] = (unsigned short)b;
    }
    __syncthreads();
    // phase d: full-lane sorted-order write (runs are dest-contiguous)
    for (int i = t; i < len; i += blockDim.x) {
        int b = binarr2[i];
        packed[gbase[b] + i - off[b]] = bufB[i];
    }
}

// ---- fused: per-bucket count + scan + dis/y4/rowptr + in-place node sort
__global__ void k_sort(unsigned int* __restrict__ packed, const int* __restrict__ bbase,
                       const float* __restrict__ x, float* __restrict__ dis,
                       float4* __restrict__ y4, int* __restrict__ rowptr, int N, int E) {
    __shared__ unsigned int buf[BUFSZ];
    __shared__ int cnt[BKT];
    __shared__ int sc[BKT];
    __shared__ int cur[BKT];
    int b = blockIdx.x, t = threadIdx.x;
    int beg = bbase[b], end = bbase[b + 1];
    int len = end - beg;
    for (int i = t; i < len; i += blockDim.x) buf[i] = packed[beg + i];
    if (t < BKT) cnt[t] = 0;
    __syncthreads();
    for (int i = t; i < len; i += blockDim.x)
        atomicAdd(&cnt[buf[i] >> 17], 1);
    __syncthreads();
    int v = 0;
    if (t < BKT) { v = cnt[t]; sc[t] = v; }
    __syncthreads();
    for (int off = 1; off < BKT; off <<= 1) {
        int u = 0;
        if (t < BKT && t >= off) u = sc[t - off];
        __syncthreads();
        if (t < BKT) sc[t] += u;
        __syncthreads();
    }
    if (t < BKT) {
        int excl = sc[t] - v;
        cur[t] = excl;
        int gi = b * BKT + t;
        if (gi < N) {
            rowptr[gi] = beg + excl;
            float di = rsqrtf((float)v + 1.0f);      // + self loop
            dis[gi] = di;
            float4 y;
            y.x = di * x[3 * gi + 0];
            y.y = di * x[3 * gi + 1];
            y.z = di * x[3 * gi + 2];
            y.w = 0.0f;
            y4[gi] = y;
        }
    }
    __syncthreads();
    for (int i = t; i < len; i += blockDim.x) {
        unsigned vv = buf[i];
        int pos = atomicAdd(&cur[vv >> 17], 1);      // LDS atomic
        packed[beg + pos] = vv & 0x1FFFF;            // plain src id, node-sorted
    }
    if (b == 0 && t == 0) rowptr[N] = E;
}

// ---- layer 1: node-parallel, 32 lanes/node gather y4 (1.6MB, L2-resident)
__global__ void k_l1(const unsigned int* __restrict__ csr, const int* __restrict__ rowptr,
                     const float4* __restrict__ y4, const float* __restrict__ dis,
                     const float* __restrict__ W1, const float* __restrict__ b1,
                     __half* __restrict__ g, int N) {
    int t = blockIdx.x * blockDim.x + threadIdx.x;
    int i = t >> 5, j = t & 31;
    if (i >= N) return;
    int beg = rowptr[i], end = rowptr[i + 1];
    float ax = 0.f, ay = 0.f, az = 0.f;
    for (int e = beg + j; e < end; e += 32) {
        float4 yv = y4[csr[e]];
        ax += yv.x; ay += yv.y; az += yv.z;
    }
#pragma unroll
    for (int m = 16; m >= 1; m >>= 1) {
        ax += __shfl_xor(ax, m, 32);
        ay += __shfl_xor(ay, m, 32);
        az += __shfl_xor(az, m, 32);
    }
    float di = dis[i];
    float4 ys = y4[i];                               // self loop (pre-scaled)
    float a0 = di * (ax + ys.x);
    float a1 = di * (ay + ys.y);
    float a2 = di * (az + ys.z);
    float h = b1[j] + a0 * W1[j] + a1 * W1[32 + j] + a2 * W1[64 + j];
    g[(size_t)i * 32 + j] = __float2half(di * fmaxf(h, 0.f));
}

// ---- layer 2 (+L3 projection): 8-wide unrolled fp16 row gathers
__global__ void k_l2(const unsigned int* __restrict__ csr, const int* __restrict__ rowptr,
                     const __half* __restrict__ g, const float* __restrict__ dis,
                     const float* __restrict__ W2, const float* __restrict__ b2,
                     const float* __restrict__ W3, float* __restrict__ q, int N) {
    int t = blockIdx.x * blockDim.x + threadIdx.x;
    int i = t >> 5, j = t & 31;
    if (i >= N) return;
    int beg = rowptr[i], end = rowptr[i + 1];
    float a0 = 0.f, a1 = 0.f, a2 = 0.f, a3 = 0.f;
    float a4 = 0.f, a5 = 0.f, a6 = 0.f, a7 = 0.f;
    for (int k0 = beg; k0 < end; k0 += 32) {
        int e = k0 + j;
        int myedge = (e < end) ? (int)csr[e] : 0;    // coalesced chunk load
        int cnt = min(32, end - k0);
        int t2 = 0;
        for (; t2 + 8 <= cnt; t2 += 8) {             // 8 independent gathers in flight
            int s0 = __shfl(myedge, t2 + 0, 32);
            int s1 = __shfl(myedge, t2 + 1, 32);
            int s2 = __shfl(myedge, t2 + 2, 32);
            int s3 = __shfl(myedge, t2 + 3, 32);
            int s4 = __shfl(myedge, t2 + 4, 32);
            int s5 = __shfl(myedge, t2 + 5, 32);
            int s6 = __shfl(myedge, t2 + 6, 32);
            int s7 = __shfl(myedge, t2 + 7, 32);
            a0 += __half2float(g[(size_t)s0 * 32 + j]);
            a1 += __half2float(g[(size_t)s1 * 32 + j]);
            a2 += __half2float(g[(size_t)s2 * 32 + j]);
            a3 += __half2float(g[(size_t)s3 * 32 + j]);
            a4 += __half2float(g[(size_t)s4 * 32 + j]);
            a5 += __half2float(g[(size_t)s5 * 32 + j]);
            a6 += __half2float(g[(size_t)s6 * 32 + j]);
            a7 += __half2float(g[(size_t)s7 * 32 + j]);
        }
        for (; t2 < cnt; t2++) {
            int s = __shfl(myedge, t2, 32);
            a0 += __half2float(g[(size_t)s * 32 + j]);
        }
    }
    float acc = ((a0 + a1) + (a2 + a3)) + ((a4 + a5) + (a6 + a7));
    float di = dis[i];
    float a = di * (acc + __half2float(g[(size_t)i * 32 + j]));   // + self loop
    float o = b2[j];
#pragma unroll
    for (int k = 0; k < 32; k++)
        o += __shfl(a, k, 32) * W2[k * 32 + j];
    float h2 = fmaxf(o, 0.f);
    float c = h2 * W3[j];
#pragma unroll
    for (int m = 16; m >= 1; m >>= 1)
        c += __shfl_xor(c, m, 32);
    if (j == 0) q[i] = di * c;                       // q = dis * p
}

// ---- layer 3: node-parallel scalar q gathers (q 400KB, L2-resident)
__global__ void k_l3(const unsigned int* __restrict__ csr, const int* __restrict__ rowptr,
                     const float* __restrict__ q, const float* __restrict__ dis,
                     const float* __restrict__ b3, float* __restrict__ out, int N) {
    int t = blockIdx.x * blockDim.x + threadIdx.x;
    int i = t >> 5, j = t & 31;
    if (i >= N) return;
    int beg = rowptr[i], end = rowptr[i + 1];
    float acc = 0.f;
    for (int e = beg + j; e < end; e += 32)
        acc += q[csr[e]];
#pragma unroll
    for (int m = 16; m >= 1; m >>= 1)
        acc += __shfl_xor(acc, m, 32);
    if (j == 0) out[i] = dis[i] * (acc + q[i]) + b3[0];
}

extern "C" void kernel_launch(void* const* d_in, const int* in_sizes, int n_in,
                              void* d_out, int out_size, void* d_ws, size_t ws_size,
                              hipStream_t stream) {
    const float* x  = (const float*)d_in[0];
    const int*   ei = (const int*)d_in[1];
    const float* W1 = (const float*)d_in[2];
    const float* b1 = (const float*)d_in[3];
    const float* W2 = (const float*)d_in[4];
    const float* b2 = (const float*)d_in[5];
    const float* W3 = (const float*)d_in[6];
    const float* b3 = (const float*)d_in[7];
    float* out = (float*)d_out;

    int N = in_sizes[0] / 3;
    int E = in_sizes[1] / 2;
    const int* src = ei;
    const int* dst = ei + E;

    // workspace (all init done in-kernel; no memset needed)
    char* w = (char*)d_ws;
    int*   hist   = (int*)w;       w += (size_t)SB * NBKT * 4;      // 4.0 MB
    int*   btot   = (int*)w;       w += (size_t)MAXNB * 4;
    int*   bbase  = (int*)w;       w += (size_t)(MAXNB + 1) * 4;
    int*   rowptr = (int*)w;       w += (size_t)(N + 1) * 4;
    float* dis    = (float*)w;     w += (size_t)N * 4;
    float* y4     = (float*)w;     w += (size_t)N * 16;
    __half* g     = (__half*)w;    w += (size_t)N * 32 * 2;          // 6.4 MB fp16
    float* q      = (float*)w;     w += (size_t)N * 4;
    unsigned int* packed = (unsigned int*)w;  w += (size_t)E * 4;    // 25.6 MB

    k_hist <<<SB, BLK, 0, stream>>>(dst, hist, E);
    k_scanA<<<NBKT, BLK, 0, stream>>>(hist, btot, NBKT);
    k_scanB<<<1, MAXNB, 0, stream>>>(btot, bbase, NBKT, E);
    k_bsort<<<SB, BLK, 0, stream>>>(src, dst, hist, bbase, packed, E);
    k_sort <<<NBKT, BLK, 0, stream>>>(packed, bbase, x, dis, (float4*)y4, rowptr, N, E);

    long long tn = (long long)N * 32;
    unsigned gn = (unsigned)((tn + BLK - 1) / BLK);
    k_l1<<<gn, BLK, 0, stream>>>(packed, rowptr, (const float4*)y4, dis, W1, b1, g, N);
    k_l2<<<gn, BLK, 0, stream>>>(packed, rowptr, g, dis, W2, b2, W3, q, N);
    k_l3<<<gn, BLK, 0, stream>>>(packed, rowptr, q, dis, b3, out, N);
}